// Round 14
// baseline (636.130 us; speedup 1.0000x reference)
//
#include <hip/hip_runtime.h>
#include <stdint.h>

typedef unsigned short ushort_t;
typedef __attribute__((ext_vector_type(4))) float f32x4;
typedef __attribute__((ext_vector_type(8))) short bf16x8;
typedef __attribute__((ext_vector_type(4))) unsigned short u16x4;

#define DEV static __device__ __forceinline__

DEV unsigned short f2bf(float f) {
  unsigned int u = __float_as_uint(f);
  unsigned int r = (u + 0x7fffu + ((u >> 16) & 1u)) >> 16;
  return (unsigned short)r;
}

DEV float bf2f(ushort_t u) { return __uint_as_float((unsigned)u << 16); }

DEV float4 ld_bf4(const ushort_t* p) {
  const u16x4 u = *(const u16x4*)p;
  float4 v;
  v.x = bf2f(u.x); v.y = bf2f(u.y); v.z = bf2f(u.z); v.w = bf2f(u.w);
  return v;
}

DEV void async16(const void* g, void* l) {
  __builtin_amdgcn_global_load_lds(
      (const __attribute__((address_space(1))) unsigned int*)g,
      (__attribute__((address_space(3))) unsigned int*)l, 16, 0, 0);
}

// ---------------------------------------------------------------------------
// C = act( [A0|A1][M,K] @ [W0|W1][N,K]^T + bias ), split at K0. bf16 in, f32
// acc. 128x128 tile, BK=32, 4 waves (2x2), 4x4 16x16x32 frags.
// XCD-affine block swizzle (bijective when Mtiles % 8 == 0 — true here).
// LDS granule swizzle (round-14): rows are 32 elem = 64 B = 4 granules of
// 16 B. Logical granule q of row r is stored at linear granule q^((r>>1)&3).
// Applied as pre-swizzled GLOBAL source (global_load_lds dest stays linear,
// rule #21) + swizzled ds_read address. Lane (fr,q)'s bank-set becomes
// 16*(fr&1) + 4*(q^((fr>>1)&3)): 16 lanes spread over 8 bank-quads, 2 each
// -> 2-way (free, m136) instead of ~8-way. Involution => bit-identical math.
// ---------------------------------------------------------------------------
template<bool SPLIT, bool RELU, bool OUTBF16>
__global__ __launch_bounds__(256, 2)
void gemm_bt(const ushort_t* __restrict__ A0, int lda0,
             const ushort_t* __restrict__ A1, int lda1,
             const ushort_t* __restrict__ W0, int ldw0,
             const ushort_t* __restrict__ W1, int ldw1,
             int K0, int K,
             const float* __restrict__ bias,
             void* __restrict__ Cv, int ldc,
             int rowsPerBatch, int cBatchStrideRows, int cRowOff)
{
  __shared__ __align__(16) ushort_t sA[2][128 * 32];
  __shared__ __align__(16) ushort_t sB[2][128 * 32];

  const int tid = threadIdx.x;
  const int w = tid >> 6, lane = tid & 63;

  const int NTl = gridDim.x;
  const int wgid = blockIdx.y * NTl + blockIdx.x;
  const int X = wgid & 7, j = wgid >> 3;
  const int n_t = j % NTl, mg = j / NTl;
  const int mBase = (X + 8 * mg) * 128;
  const int nBase = n_t * 128;

  const int wr = w >> 1, wc = w & 1;

  f32x4 acc[4][4] = {};

  auto stage = [&](int kt, int buf) {
    const int k0 = kt * 32;
    const ushort_t* Ap = A0; int lda = lda0; int ka = k0;
    const ushort_t* Wp = W0; int ldw = ldw0; int kw = k0;
    if (SPLIT && k0 >= K0) {
      Ap = A1; lda = lda1; ka = k0 - K0;
      Wp = W1; ldw = ldw1; kw = k0 - K0;
    }
#pragma unroll
    for (int c = 0; c < 2; ++c) {
      const int eb = (w * 2 + c) * 512;          // wave-uniform LDS element base
      const int e = eb + lane * 8;               // this lane's linear LDS slot
      const int row = e >> 5;                    // 0..127
      const int gc = ((e >> 3) & 3) ^ ((row >> 1) & 3);  // logical granule
      async16(Ap + (size_t)(mBase + row) * lda + (ka + gc * 8), &sA[buf][eb]);
    }
#pragma unroll
    for (int c = 0; c < 2; ++c) {
      const int eb = (w * 2 + c) * 512;
      const int e = eb + lane * 8;
      const int row = e >> 5;
      const int gc = ((e >> 3) & 3) ^ ((row >> 1) & 3);
      async16(Wp + (size_t)(nBase + row) * ldw + (kw + gc * 8), &sB[buf][eb]);
    }
  };

  const int nkt = K >> 5;
  stage(0, 0);
  int cur = 0;
  const int fr = lane & 15, q4 = lane >> 4;

  for (int kt = 0; kt < nkt; ++kt) {
    __syncthreads();                     // vmcnt drained before barrier: tile ready
    if (kt + 1 < nkt) stage(kt + 1, cur ^ 1);
    bf16x8 a[4], b[4];
#pragma unroll
    for (int m = 0; m < 4; ++m) {
      const int row = wr * 64 + m * 16 + fr;
      const int gc = q4 ^ ((row >> 1) & 3);      // swizzled read granule
      a[m] = *(const bf16x8*)&sA[cur][row * 32 + gc * 8];
    }
#pragma unroll
    for (int n = 0; n < 4; ++n) {
      const int row = wc * 64 + n * 16 + fr;
      const int gc = q4 ^ ((row >> 1) & 3);
      b[n] = *(const bf16x8*)&sB[cur][row * 32 + gc * 8];
    }
#pragma unroll
    for (int m = 0; m < 4; ++m)
#pragma unroll
      for (int n = 0; n < 4; ++n)
        acc[m][n] = __builtin_amdgcn_mfma_f32_16x16x32_bf16(a[m], b[n], acc[m][n], 0, 0, 0);
    cur ^= 1;
  }

  const int bIdx = mBase / rowsPerBatch;
  const int rowBase = bIdx * cBatchStrideRows + cRowOff + (mBase - bIdx * rowsPerBatch);

  float* Cf = (float*)Cv;
  ushort_t* Cb = (ushort_t*)Cv;
  const int q = lane >> 4;
#pragma unroll
  for (int n = 0; n < 4; ++n) {
    const int gcol = nBase + wc * 64 + n * 16 + fr;
    const float bv = bias[gcol];
#pragma unroll
    for (int m = 0; m < 4; ++m) {
      const int lr = wr * 64 + m * 16 + q * 4;
#pragma unroll
      for (int j4 = 0; j4 < 4; ++j4) {
        float v = acc[m][n][j4] + bv;
        if (RELU) v = v > 0.f ? v : 0.01f * v;
        const size_t idx = (size_t)(rowBase + lr + j4) * ldc + gcol;
        if (OUTBF16) Cb[idx] = f2bf(v); else Cf[idx] = v;
      }
    }
  }
}

DEV int start_at(const void* start, int m, size_t idx) {
  return m ? (int)((const signed char*)start)[idx] : ((const int*)start)[idx];
}

// ---------------------------------------------------------------------------
// Fused weight prep (one dispatch). Block ranges:
//   [0,6400)      : 7 bf16-cvt segments (dst cols=1024, quad-vectorized)
//   [6400,7424)   : wiT transpose (256x1024)
//   [7424,10496)  : 3x fold_bias
//   10496         : zeroB     10497 : detect_mode
// ---------------------------------------------------------------------------
__global__ __launch_bounds__(256)
void prep_all(const float* __restrict__ Wp, const float* __restrict__ Wf,
              const float* __restrict__ Wo, const float* __restrict__ Wi,
              const float* __restrict__ bi, const float* __restrict__ bp,
              const float* __restrict__ bf_,
              ushort_t* __restrict__ wp1, ushort_t* __restrict__ wf0a,
              ushort_t* __restrict__ wf1a, ushort_t* __restrict__ wp0b,
              ushort_t* __restrict__ wf0b, ushort_t* __restrict__ wf1b,
              ushort_t* __restrict__ wob, ushort_t* __restrict__ wiT,
              float* __restrict__ bz0, float* __restrict__ bc0,
              float* __restrict__ bc1, float* __restrict__ zeroB,
              const int* __restrict__ startW, int* __restrict__ mode) {
  const int blk = blockIdx.x, tid = threadIdx.x;
  const int H = 1024;
  __shared__ float redf[256];
  __shared__ int redi[256];

  if (blk < 6400) {
    const int gq = blk * 256 + tid;
    const float* src; ushort_t* dst; int stride; int q;
    if (gq < 262144)       { q = gq;           src = Wp + (size_t)H * H;         dst = wp1;  stride = H; }
    else if (gq < 524288)  { q = gq - 262144;  src = Wf;                         dst = wf0a; stride = 2 * H; }
    else if (gq < 786432)  { q = gq - 524288;  src = Wf + (size_t)H * 2 * H;     dst = wf1a; stride = 2 * H; }
    else if (gq < 1048576) { q = gq - 786432;  src = Wp;                         dst = wp0b; stride = H; }
    else if (gq < 1310720) { q = gq - 1048576; src = Wf + H;                     dst = wf0b; stride = 2 * H; }
    else if (gq < 1572864) { q = gq - 1310720; src = Wf + (size_t)H * 2 * H + H; dst = wf1b; stride = 2 * H; }
    else                   { q = gq - 1572864; src = Wo;                         dst = wob;  stride = H; }
    const int row = q >> 8, cq = q & 255;
    const float4 v = *(const float4*)(src + (size_t)row * stride + cq * 4);
    u16x4 o;
    o.x = f2bf(v.x); o.y = f2bf(v.y); o.z = f2bf(v.z); o.w = f2bf(v.w);
    *(u16x4*)(dst + (size_t)row * 1024 + cq * 4) = o;
  } else if (blk < 7424) {
    const int i = (blk - 6400) * 256 + tid;
    const int d = i >> 10, h = i & 1023;
    wiT[(size_t)d * 1024 + h] = f2bf(Wi[(size_t)h * 256 + d]);
  } else if (blk < 10496) {
    const int f = blk - 7424;
    const int which = f >> 10, g = f & 1023;
    const float* A; int ldA; const float* bin; float* bout;
    if (which == 0)      { A = Wp;                         ldA = H;     bin = bp;      bout = bz0; }
    else if (which == 1) { A = Wf + H;                     ldA = 2 * H; bin = bf_;     bout = bc0; }
    else                 { A = Wf + (size_t)H * 2 * H + H; ldA = 2 * H; bin = bf_ + H; bout = bc1; }
    float acc = 0.f;
    for (int h = tid; h < 1024; h += 256) acc += A[(size_t)g * ldA + h] * bi[h];
    redf[tid] = acc;
    __syncthreads();
    for (int s = 128; s > 0; s >>= 1) {
      if (tid < s) redf[tid] += redf[tid + s];
      __syncthreads();
    }
    if (tid == 0) bout[g] = bin[g] + redf[0];
  } else if (blk == 10496) {
    zeroB[tid] = 0.f;
  } else {
    int acc = 0;
    for (int i = tid; i < 8192; i += 256) acc |= startW[i];
    redi[tid] = acc;
    __syncthreads();
    for (int s = 128; s > 0; s >>= 1) {
      if (tid < s) redi[tid] |= redi[tid + s];
      __syncthreads();
    }
    if (tid == 0) *mode = (redi[0] & ~1) ? 1 : 0;
  }
}

// ---------------------------------------------------------------------------
// Parallel segmented scan over bf16 z, T-blocks of TB=16.
// ---------------------------------------------------------------------------
#define TB 16

__global__ __launch_bounds__(256)
void scan_p1(const ushort_t* __restrict__ z, const void* __restrict__ start,
             const int* __restrict__ mode, float* __restrict__ aggS,
             int* __restrict__ aggF, int t0, int Tc, int NT) {
  const int id = blockIdx.x * 256 + threadIdx.x;
  const int g = id & 1023;
  const int r = id >> 10;                 // 0 .. 8*NT-1
  const int b = r / NT, tb = r - b * NT;
  const int m = *mode;
  const size_t sbase = (size_t)b * 4096 + t0 + tb * TB;
  const ushort_t* zp = z + ((size_t)b * Tc + tb * TB) * 1024 + g;
  float ls = 0.f;
  int lf = 0;
  for (int t = 0; t < TB; ++t) {
    const float zv = bf2f(zp[(size_t)t * 1024]);
    const int st = start_at(start, m, sbase + t);
    ls = st ? zv : (ls + zv);
    lf |= st;
  }
  aggS[(size_t)r * 1024 + g] = ls;
  if (g == 0) aggF[r] = lf;
}

__global__ __launch_bounds__(256)
void scan_p2(const float* __restrict__ aggS, const int* __restrict__ aggF,
             float* __restrict__ prefixS, float* __restrict__ carry,
             int first, int NT) {
  const int id = blockIdx.x * 256 + threadIdx.x;   // 0..8191
  const int b = id >> 10, g = id & 1023;
  float s = first ? -6.93147180559945f : carry[id];
  for (int tb = 0; tb < NT; ++tb) {
    const size_t r = (size_t)(b * NT + tb);
    prefixS[r * 1024 + g] = s;
    const float sum = aggS[r * 1024 + g];
    s = aggF[r] ? sum : (s + sum);
  }
  carry[id] = s;
}

// P3 + fused softmax, wave-per-row: lane l holds g = 4l + 256k.
__global__ __launch_bounds__(64)
void scan_p3sm_wave(const ushort_t* __restrict__ z, const void* __restrict__ start,
                    const int* __restrict__ mode, const float* __restrict__ prefixS,
                    ushort_t* __restrict__ P, int t0, int Tc, int NT) {
  const int r = blockIdx.x;
  const int b = r / NT, tb = r - b * NT;
  const int l = threadIdx.x;              // 0..63
  const int m = *mode;
  const size_t sbase = (size_t)b * 4096 + t0 + tb * TB;
  const ushort_t* zp = z + ((size_t)b * Tc + tb * TB) * 1024 + 4 * l;
  ushort_t* pp = P + ((size_t)b * Tc + tb * TB) * 1024 + 4 * l;

  float4 s[4], zv[4];
#pragma unroll
  for (int k = 0; k < 4; ++k)
    s[k] = *(const float4*)(prefixS + (size_t)r * 1024 + 4 * l + 256 * k);
#pragma unroll
  for (int k = 0; k < 4; ++k)
    zv[k] = ld_bf4(zp + 256 * k);

  for (int t = 0; t < TB; ++t) {
    float4 zn[4];
    if (t + 1 < TB) {
#pragma unroll
      for (int k = 0; k < 4; ++k)
        zn[k] = ld_bf4(zp + (size_t)(t + 1) * 1024 + 256 * k);
    } else {
#pragma unroll
      for (int k = 0; k < 4; ++k) zn[k] = zv[k];
    }
    const int st = start_at(start, m, sbase + t);
    if (st) {
#pragma unroll
      for (int k = 0; k < 4; ++k) s[k] = zv[k];
    } else {
#pragma unroll
      for (int k = 0; k < 4; ++k) {
        s[k].x += zv[k].x; s[k].y += zv[k].y;
        s[k].z += zv[k].z; s[k].w += zv[k].w;
      }
    }
    float mx = fmaxf(fmaxf(s[0].x, s[0].y), fmaxf(s[0].z, s[0].w));
#pragma unroll
    for (int k = 1; k < 4; ++k)
      mx = fmaxf(mx, fmaxf(fmaxf(s[k].x, s[k].y), fmaxf(s[k].z, s[k].w)));
#pragma unroll
    for (int o = 32; o > 0; o >>= 1) mx = fmaxf(mx, __shfl_xor(mx, o));
    float4 e[4];
    float sum = 0.f;
#pragma unroll
    for (int k = 0; k < 4; ++k) {
      e[k].x = __expf(s[k].x - mx); e[k].y = __expf(s[k].y - mx);
      e[k].z = __expf(s[k].z - mx); e[k].w = __expf(s[k].w - mx);
      sum += (e[k].x + e[k].y) + (e[k].z + e[k].w);
    }
#pragma unroll
    for (int o = 32; o > 0; o >>= 1) sum += __shfl_xor(sum, o);
    const float inv = 1.0f / sum;
#pragma unroll
    for (int k = 0; k < 4; ++k) {
      u16x4 o4;
      o4.x = f2bf(e[k].x * inv); o4.y = f2bf(e[k].y * inv);
      o4.z = f2bf(e[k].z * inv); o4.w = f2bf(e[k].w * inv);
      *(u16x4*)(pp + (size_t)t * 1024 + 256 * k) = o4;
    }
#pragma unroll
    for (int k = 0; k < 4; ++k) zv[k] = zn[k];
  }
}

// ---------------------------------------------------------------------------
__global__ __launch_bounds__(256)
void cvt_x_chunk(const float* __restrict__ x, ushort_t* __restrict__ dst,
                 int t0, int tcShift, int nq) {
  const int i = blockIdx.x * 256 + threadIdx.x;
  if (i >= nq) return;
  const int row = i >> 6, cq = i & 63;
  const int b = row >> tcShift, tl = row & ((1 << tcShift) - 1);
  const float4 v = *(const float4*)(x + ((size_t)b * 4096 + t0 + tl) * 256 + cq * 4);
  u16x4 o;
  o.x = f2bf(v.x); o.y = f2bf(v.y); o.z = f2bf(v.z); o.w = f2bf(v.w);
  *(u16x4*)(dst + (size_t)row * 256 + cq * 4) = o;
}

// ---------------------------------------------------------------------------
__global__ __launch_bounds__(256)
void fill_diag(float* __restrict__ out, int n, float v) {
  const int i = blockIdx.x * 256 + threadIdx.x;
  if (i < n) out[i] = v;
}

// ---------------------------------------------------------------------------
extern "C" void kernel_launch(void* const* d_in, const int* in_sizes, int n_in,
                              void* d_out, int out_size, void* d_ws, size_t ws_size,
                              hipStream_t stream) {
  const float* x    = (const float*)d_in[0];
  const void* start = (const void*)d_in[1];
  const float* Wi   = (const float*)d_in[2];
  const float* bi   = (const float*)d_in[3];
  const float* Wp   = (const float*)d_in[4];
  const float* bp   = (const float*)d_in[5];
  const float* Wf   = (const float*)d_in[6];
  const float* bf_  = (const float*)d_in[7];
  const float* Wo   = (const float*)d_in[8];
  const float* bo   = (const float*)d_in[9];

  const int T = 4096, H = 1024;

  char* ws = (char*)d_ws;
  size_t off = 0;
  auto alloc = [&](size_t bytes) {
    char* p = ws + off; off += (bytes + 255) & ~(size_t)255; return p;
  };

  // --- fixed region (~41 MB incl. NT<=256 scan scratch) ---
  ushort_t* wz0  = (ushort_t*)alloc((size_t)H * 256 * 2);
  ushort_t* wc0  = (ushort_t*)alloc((size_t)H * 256 * 2);
  ushort_t* wc1  = (ushort_t*)alloc((size_t)H * 256 * 2);
  ushort_t* wp1  = (ushort_t*)alloc((size_t)H * H * 2);
  ushort_t* wf0a = (ushort_t*)alloc((size_t)H * H * 2);
  ushort_t* wf1a = (ushort_t*)alloc((size_t)H * H * 2);
  ushort_t* wob  = (ushort_t*)alloc((size_t)256 * H * 2);
  ushort_t* wiT  = (ushort_t*)alloc((size_t)256 * H * 2);
  ushort_t* wp0b = (ushort_t*)alloc((size_t)H * H * 2);
  ushort_t* wf0b = (ushort_t*)alloc((size_t)H * H * 2);
  ushort_t* wf1b = (ushort_t*)alloc((size_t)H * H * 2);
  float* bz0 = (float*)alloc(H * 4);
  float* bc0 = (float*)alloc(H * 4);
  float* bc1 = (float*)alloc(H * 4);
  float* zeroB = (float*)alloc(256 * 4);
  float* carry0 = (float*)alloc(8192 * 4);
  float* carry1 = (float*)alloc(8192 * 4);
  int* mode = (int*)alloc(256);
  float* aggS    = (float*)alloc((size_t)8 * 256 * 1024 * 4);   // 8 MB (NT<=256)
  float* prefixS = (float*)alloc((size_t)8 * 256 * 1024 * 4);   // 8 MB
  int*   aggF    = (int*)alloc(8 * 256 * 4);
  const size_t fixed = off;

  // --- choose largest fitting T-chunk ---
  auto chunkBytes = [&](int Tc) -> size_t {
    const size_t Mc = (size_t)8 * Tc;
    return Mc * 256 * 2 + 256 + Mc * H * 2 + 256 +
           Mc * H * 2 + 256 + Mc * H * 2 + 256;
  };
  int Tc = 4096;
  while (Tc > 128 && fixed + chunkBytes(Tc) > ws_size) Tc >>= 1;
  if (fixed + chunkBytes(Tc) > ws_size) {
    fill_diag<<<dim3((out_size + 255) / 256), dim3(256), 0, stream>>>(
        (float*)d_out, out_size, (float)(ws_size >> 20));
    return;
  }
  const int Mc = 8 * Tc;
  const int NT = Tc / TB;
  const int tcShift = __builtin_ctz((unsigned)Tc);
  ushort_t* xbc  = (ushort_t*)alloc((size_t)Mc * 256 * 2);
  ushort_t* zbuf = (ushort_t*)alloc((size_t)Mc * H * 2);   // bf16 z
  ushort_t* pbuf = (ushort_t*)alloc((size_t)Mc * H * 2);
  ushort_t* hbuf = (ushort_t*)alloc((size_t)Mc * H * 2);

  const dim3 blk(256);

  auto run_scan_sm = [&](ushort_t* z, float* carry, int first, int t0) {
    scan_p1<<<dim3(32 * NT), blk, 0, stream>>>(z, start, mode, aggS, aggF, t0, Tc, NT);
    scan_p2<<<dim3(32), blk, 0, stream>>>(aggS, aggF, prefixS, carry, first, NT);
    scan_p3sm_wave<<<dim3(8 * NT), dim3(64), 0, stream>>>(
        z, start, mode, prefixS, pbuf, t0, Tc, NT);
  };

  // --- weight prep: ONE fused dispatch + 3 MFMA fold-GEMMs ---
  prep_all<<<dim3(10498), blk, 0, stream>>>(
      Wp, Wf, Wo, Wi, bi, bp, bf_,
      wp1, wf0a, wf1a, wp0b, wf0b, wf1b, wob, wiT,
      bz0, bc0, bc1, zeroB, (const int*)start, mode);

  gemm_bt<false, false, true><<<dim3(2, 8), blk, 0, stream>>>(
      wp0b, H, wp0b, H, wiT, H, wiT, H, H, H, zeroB, wz0, 256, 1024, 0, 0);
  gemm_bt<false, false, true><<<dim3(2, 8), blk, 0, stream>>>(
      wf0b, H, wf0b, H, wiT, H, wiT, H, H, H, zeroB, wc0, 256, 1024, 0, 0);
  gemm_bt<false, false, true><<<dim3(2, 8), blk, 0, stream>>>(
      wf1b, H, wf1b, H, wiT, H, wiT, H, H, H, zeroB, wc1, 256, 1024, 0, 0);

  // --- chunked pipeline (Tc=4096 -> single chunk) ---
  const int nch = T / Tc;
  for (int c = 0; c < nch; ++c) {
    const int t0 = c * Tc;
    cvt_x_chunk<<<dim3((Mc * 64 + 255) / 256), blk, 0, stream>>>(
        x, xbc, t0, tcShift, Mc * 64);
    // z0 = x @ (Wp0·Wi)^T + (bp0 + Wp0·bi)   -> bf16 z
    gemm_bt<false, false, true><<<dim3(H / 128, Mc / 128), blk, 0, stream>>>(
        xbc, 256, xbc, 256, wz0, 256, wz0, 256, 256, 256, bz0, zbuf, H, Mc, 0, 0);
    run_scan_sm(zbuf, carry0, c == 0, t0);
    // h0 = leaky( p @ Wf0a^T + x @ (WfB0·Wi)^T + bc0 )
    gemm_bt<true, true, true><<<dim3(H / 128, Mc / 128), blk, 0, stream>>>(
        pbuf, H, xbc, 256, wf0a, H, wc0, 256, H, H + 256, bc0, hbuf, H, Mc, 0, 0);
    // z1 = h0 @ Wp1^T + bp1   -> bf16 z
    gemm_bt<false, false, true><<<dim3(H / 128, Mc / 128), blk, 0, stream>>>(
        hbuf, H, hbuf, H, wp1, H, wp1, H, H, H, bp + H, zbuf, H, Mc, 0, 0);
    run_scan_sm(zbuf, carry1, c == 0, t0);
    // h1 = leaky( p @ Wf1a^T + x @ (WfB1·Wi)^T + bc1 )
    gemm_bt<true, true, true><<<dim3(H / 128, Mc / 128), blk, 0, stream>>>(
        pbuf, H, xbc, 256, wf1a, H, wc1, 256, H, H + 256, bc1, hbuf, H, Mc, 0, 0);
    // out = h1 @ Wo^T + bo  (batch-strided C write into d_out)
    gemm_bt<false, false, false><<<dim3(256 / 128, Mc / 128), blk, 0, stream>>>(
        hbuf, H, hbuf, H, wob, H, wob, H, H, H, bo, (float*)d_out, 256,
        Tc, T, t0);
  }
}

// Round 15
// 619.385 us; speedup vs baseline: 1.0270x; 1.0270x over previous
//
#include <hip/hip_runtime.h>
#include <stdint.h>

typedef unsigned short ushort_t;
typedef __attribute__((ext_vector_type(4))) float f32x4;
typedef __attribute__((ext_vector_type(8))) short bf16x8;
typedef __attribute__((ext_vector_type(4))) unsigned short u16x4;

#define DEV static __device__ __forceinline__

DEV unsigned short f2bf(float f) {
  unsigned int u = __float_as_uint(f);
  unsigned int r = (u + 0x7fffu + ((u >> 16) & 1u)) >> 16;
  return (unsigned short)r;
}

DEV float bf2f(ushort_t u) { return __uint_as_float((unsigned)u << 16); }

DEV float4 ld_bf4(const ushort_t* p) {
  const u16x4 u = *(const u16x4*)p;
  float4 v;
  v.x = bf2f(u.x); v.y = bf2f(u.y); v.z = bf2f(u.z); v.w = bf2f(u.w);
  return v;
}

DEV void async16(const void* g, void* l) {
  __builtin_amdgcn_global_load_lds(
      (const __attribute__((address_space(1))) unsigned int*)g,
      (__attribute__((address_space(3))) unsigned int*)l, 16, 0, 0);
}

// ---------------------------------------------------------------------------
// C = act( [A0|A1][M,K] @ [W0|W1][N,K]^T + bias ), split at K0. bf16 in, f32
// acc. 128x128 tile, BK=32, 4 waves (2x2), 4x4 16x16x32 frags.
// XCD-affine block swizzle (bijective when Mtiles % 8 == 0 — true here).
// LDS granule swizzle (r14): conflicts 1.05e7 -> 0 (kept: free).
// Round-15: MFMA operands SWAPPED — mfma(b,a) yields D^T (bit-exact since
// D[i][j]=dot(rowA_i,rowB_j)); per-lane j=0..3 now span 4 CONSECUTIVE C
// columns at a FIXED row -> packed u16x4/float4 stores (16 instead of 64
// scattered 2-byte stores per thread).
// ---------------------------------------------------------------------------
template<bool SPLIT, bool RELU, bool OUTBF16>
__global__ __launch_bounds__(256, 2)
void gemm_bt(const ushort_t* __restrict__ A0, int lda0,
             const ushort_t* __restrict__ A1, int lda1,
             const ushort_t* __restrict__ W0, int ldw0,
             const ushort_t* __restrict__ W1, int ldw1,
             int K0, int K,
             const float* __restrict__ bias,
             void* __restrict__ Cv, int ldc,
             int rowsPerBatch, int cBatchStrideRows, int cRowOff)
{
  __shared__ __align__(16) ushort_t sA[2][128 * 32];
  __shared__ __align__(16) ushort_t sB[2][128 * 32];

  const int tid = threadIdx.x;
  const int w = tid >> 6, lane = tid & 63;

  const int NTl = gridDim.x;
  const int wgid = blockIdx.y * NTl + blockIdx.x;
  const int X = wgid & 7, j = wgid >> 3;
  const int n_t = j % NTl, mg = j / NTl;
  const int mBase = (X + 8 * mg) * 128;
  const int nBase = n_t * 128;

  const int wr = w >> 1, wc = w & 1;

  f32x4 acc[4][4] = {};

  auto stage = [&](int kt, int buf) {
    const int k0 = kt * 32;
    const ushort_t* Ap = A0; int lda = lda0; int ka = k0;
    const ushort_t* Wp = W0; int ldw = ldw0; int kw = k0;
    if (SPLIT && k0 >= K0) {
      Ap = A1; lda = lda1; ka = k0 - K0;
      Wp = W1; ldw = ldw1; kw = k0 - K0;
    }
#pragma unroll
    for (int c = 0; c < 2; ++c) {
      const int eb = (w * 2 + c) * 512;          // wave-uniform LDS element base
      const int e = eb + lane * 8;               // this lane's linear LDS slot
      const int row = e >> 5;                    // 0..127
      const int gc = ((e >> 3) & 3) ^ ((row >> 1) & 3);  // logical granule
      async16(Ap + (size_t)(mBase + row) * lda + (ka + gc * 8), &sA[buf][eb]);
    }
#pragma unroll
    for (int c = 0; c < 2; ++c) {
      const int eb = (w * 2 + c) * 512;
      const int e = eb + lane * 8;
      const int row = e >> 5;
      const int gc = ((e >> 3) & 3) ^ ((row >> 1) & 3);
      async16(Wp + (size_t)(nBase + row) * ldw + (kw + gc * 8), &sB[buf][eb]);
    }
  };

  const int nkt = K >> 5;
  stage(0, 0);
  int cur = 0;
  const int fr = lane & 15, q4 = lane >> 4;

  for (int kt = 0; kt < nkt; ++kt) {
    __syncthreads();                     // vmcnt drained before barrier: tile ready
    if (kt + 1 < nkt) stage(kt + 1, cur ^ 1);
    bf16x8 a[4], b[4];
#pragma unroll
    for (int m = 0; m < 4; ++m) {
      const int row = wr * 64 + m * 16 + fr;
      const int gc = q4 ^ ((row >> 1) & 3);      // swizzled read granule
      a[m] = *(const bf16x8*)&sA[cur][row * 32 + gc * 8];
    }
#pragma unroll
    for (int n = 0; n < 4; ++n) {
      const int row = wc * 64 + n * 16 + fr;
      const int gc = q4 ^ ((row >> 1) & 3);
      b[n] = *(const bf16x8*)&sB[cur][row * 32 + gc * 8];
    }
#pragma unroll
    for (int m = 0; m < 4; ++m)
#pragma unroll
      for (int n = 0; n < 4; ++n)   // SWAPPED: D^T fragment (row<->fr, col<->j)
        acc[m][n] = __builtin_amdgcn_mfma_f32_16x16x32_bf16(b[n], a[m], acc[m][n], 0, 0, 0);
    cur ^= 1;
  }

  const int bIdx = mBase / rowsPerBatch;
  const int rowBase = bIdx * cBatchStrideRows + cRowOff + (mBase - bIdx * rowsPerBatch);

  float* Cf = (float*)Cv;
  ushort_t* Cb = (ushort_t*)Cv;
#pragma unroll
  for (int m = 0; m < 4; ++m) {
    const int grow = rowBase + wr * 64 + m * 16 + fr;   // fixed per lane
    ushort_t* rowB = Cb + (size_t)grow * ldc;
    float*    rowF = Cf + (size_t)grow * ldc;
#pragma unroll
    for (int n = 0; n < 4; ++n) {
      const int nc = nBase + wc * 64 + n * 16 + q4 * 4;  // 4 consecutive cols
      const float4 bv = *(const float4*)(bias + nc);
      float v0 = acc[m][n][0] + bv.x, v1 = acc[m][n][1] + bv.y;
      float v2 = acc[m][n][2] + bv.z, v3 = acc[m][n][3] + bv.w;
      if (RELU) {
        v0 = v0 > 0.f ? v0 : 0.01f * v0; v1 = v1 > 0.f ? v1 : 0.01f * v1;
        v2 = v2 > 0.f ? v2 : 0.01f * v2; v3 = v3 > 0.f ? v3 : 0.01f * v3;
      }
      if (OUTBF16) {
        u16x4 o;
        o.x = f2bf(v0); o.y = f2bf(v1); o.z = f2bf(v2); o.w = f2bf(v3);
        *(u16x4*)(rowB + nc) = o;
      } else {
        float4 o; o.x = v0; o.y = v1; o.z = v2; o.w = v3;
        *(float4*)(rowF + nc) = o;
      }
    }
  }
}

DEV int start_at(const void* start, int m, size_t idx) {
  return m ? (int)((const signed char*)start)[idx] : ((const int*)start)[idx];
}

// ---------------------------------------------------------------------------
// Fused prep (one dispatch). Block ranges:
//   [0,6400)        : 7 bf16-cvt segments (dst cols=1024, quad-vectorized)
//   [6400,7424)     : wiT transpose (256x1024)
//   [7424,10496)    : 3x fold_bias
//   10496           : zeroB     10497 : detect_mode
//   [10498,10498+xb): x chunk-0 -> bf16 (round-15: absorbs cvt_x launch)
// ---------------------------------------------------------------------------
__global__ __launch_bounds__(256)
void prep_all(const float* __restrict__ Wp, const float* __restrict__ Wf,
              const float* __restrict__ Wo, const float* __restrict__ Wi,
              const float* __restrict__ bi, const float* __restrict__ bp,
              const float* __restrict__ bf_,
              ushort_t* __restrict__ wp1, ushort_t* __restrict__ wf0a,
              ushort_t* __restrict__ wf1a, ushort_t* __restrict__ wp0b,
              ushort_t* __restrict__ wf0b, ushort_t* __restrict__ wf1b,
              ushort_t* __restrict__ wob, ushort_t* __restrict__ wiT,
              float* __restrict__ bz0, float* __restrict__ bc0,
              float* __restrict__ bc1, float* __restrict__ zeroB,
              const int* __restrict__ startW, int* __restrict__ mode,
              const float* __restrict__ x, ushort_t* __restrict__ xbc,
              int tcShift) {
  const int blk = blockIdx.x, tid = threadIdx.x;
  const int H = 1024;
  __shared__ float redf[256];
  __shared__ int redi[256];

  if (blk < 6400) {
    const int gq = blk * 256 + tid;
    const float* src; ushort_t* dst; int stride; int q;
    if (gq < 262144)       { q = gq;           src = Wp + (size_t)H * H;         dst = wp1;  stride = H; }
    else if (gq < 524288)  { q = gq - 262144;  src = Wf;                         dst = wf0a; stride = 2 * H; }
    else if (gq < 786432)  { q = gq - 524288;  src = Wf + (size_t)H * 2 * H;     dst = wf1a; stride = 2 * H; }
    else if (gq < 1048576) { q = gq - 786432;  src = Wp;                         dst = wp0b; stride = H; }
    else if (gq < 1310720) { q = gq - 1048576; src = Wf + H;                     dst = wf0b; stride = 2 * H; }
    else if (gq < 1572864) { q = gq - 1310720; src = Wf + (size_t)H * 2 * H + H; dst = wf1b; stride = 2 * H; }
    else                   { q = gq - 1572864; src = Wo;                         dst = wob;  stride = H; }
    const int row = q >> 8, cq = q & 255;
    const float4 v = *(const float4*)(src + (size_t)row * stride + cq * 4);
    u16x4 o;
    o.x = f2bf(v.x); o.y = f2bf(v.y); o.z = f2bf(v.z); o.w = f2bf(v.w);
    *(u16x4*)(dst + (size_t)row * 1024 + cq * 4) = o;
  } else if (blk < 7424) {
    const int i = (blk - 6400) * 256 + tid;
    const int d = i >> 10, h = i & 1023;
    wiT[(size_t)d * 1024 + h] = f2bf(Wi[(size_t)h * 256 + d]);
  } else if (blk < 10496) {
    const int f = blk - 7424;
    const int which = f >> 10, g = f & 1023;
    const float* A; int ldA; const float* bin; float* bout;
    if (which == 0)      { A = Wp;                         ldA = H;     bin = bp;      bout = bz0; }
    else if (which == 1) { A = Wf + H;                     ldA = 2 * H; bin = bf_;     bout = bc0; }
    else                 { A = Wf + (size_t)H * 2 * H + H; ldA = 2 * H; bin = bf_ + H; bout = bc1; }
    float acc = 0.f;
    for (int h = tid; h < 1024; h += 256) acc += A[(size_t)g * ldA + h] * bi[h];
    redf[tid] = acc;
    __syncthreads();
    for (int s = 128; s > 0; s >>= 1) {
      if (tid < s) redf[tid] += redf[tid + s];
      __syncthreads();
    }
    if (tid == 0) bout[g] = bin[g] + redf[0];
  } else if (blk == 10496) {
    zeroB[tid] = 0.f;
  } else if (blk == 10497) {
    int acc = 0;
    for (int i = tid; i < 8192; i += 256) acc |= startW[i];
    redi[tid] = acc;
    __syncthreads();
    for (int s = 128; s > 0; s >>= 1) {
      if (tid < s) redi[tid] |= redi[tid + s];
      __syncthreads();
    }
    if (tid == 0) *mode = (redi[0] & ~1) ? 1 : 0;
  } else {
    // x chunk-0 conversion (t0 = 0)
    const int i = (blk - 10498) * 256 + tid;   // quad index
    const int row = i >> 6, cq = i & 63;
    const int b = row >> tcShift, tl = row & ((1 << tcShift) - 1);
    const float4 v = *(const float4*)(x + ((size_t)b * 4096 + tl) * 256 + cq * 4);
    u16x4 o;
    o.x = f2bf(v.x); o.y = f2bf(v.y); o.z = f2bf(v.z); o.w = f2bf(v.w);
    *(u16x4*)(xbc + (size_t)row * 256 + cq * 4) = o;
  }
}

// ---------------------------------------------------------------------------
// Parallel segmented scan over bf16 z, T-blocks of TB=16.
// ---------------------------------------------------------------------------
#define TB 16

__global__ __launch_bounds__(256)
void scan_p1(const ushort_t* __restrict__ z, const void* __restrict__ start,
             const int* __restrict__ mode, float* __restrict__ aggS,
             int* __restrict__ aggF, int t0, int Tc, int NT) {
  const int id = blockIdx.x * 256 + threadIdx.x;
  const int g = id & 1023;
  const int r = id >> 10;                 // 0 .. 8*NT-1
  const int b = r / NT, tb = r - b * NT;
  const int m = *mode;
  const size_t sbase = (size_t)b * 4096 + t0 + tb * TB;
  const ushort_t* zp = z + ((size_t)b * Tc + tb * TB) * 1024 + g;
  float ls = 0.f;
  int lf = 0;
  for (int t = 0; t < TB; ++t) {
    const float zv = bf2f(zp[(size_t)t * 1024]);
    const int st = start_at(start, m, sbase + t);
    ls = st ? zv : (ls + zv);
    lf |= st;
  }
  aggS[(size_t)r * 1024 + g] = ls;
  if (g == 0) aggF[r] = lf;
}

__global__ __launch_bounds__(256)
void scan_p2(const float* __restrict__ aggS, const int* __restrict__ aggF,
             float* __restrict__ prefixS, float* __restrict__ carry,
             int first, int NT) {
  const int id = blockIdx.x * 256 + threadIdx.x;   // 0..8191
  const int b = id >> 10, g = id & 1023;
  float s = first ? -6.93147180559945f : carry[id];
  for (int tb = 0; tb < NT; ++tb) {
    const size_t r = (size_t)(b * NT + tb);
    prefixS[r * 1024 + g] = s;
    const float sum = aggS[r * 1024 + g];
    s = aggF[r] ? sum : (s + sum);
  }
  carry[id] = s;
}

// P3 + fused softmax, wave-per-row: lane l holds g = 4l + 256k.
__global__ __launch_bounds__(64)
void scan_p3sm_wave(const ushort_t* __restrict__ z, const void* __restrict__ start,
                    const int* __restrict__ mode, const float* __restrict__ prefixS,
                    ushort_t* __restrict__ P, int t0, int Tc, int NT) {
  const int r = blockIdx.x;
  const int b = r / NT, tb = r - b * NT;
  const int l = threadIdx.x;              // 0..63
  const int m = *mode;
  const size_t sbase = (size_t)b * 4096 + t0 + tb * TB;
  const ushort_t* zp = z + ((size_t)b * Tc + tb * TB) * 1024 + 4 * l;
  ushort_t* pp = P + ((size_t)b * Tc + tb * TB) * 1024 + 4 * l;

  float4 s[4], zv[4];
#pragma unroll
  for (int k = 0; k < 4; ++k)
    s[k] = *(const float4*)(prefixS + (size_t)r * 1024 + 4 * l + 256 * k);
#pragma unroll
  for (int k = 0; k < 4; ++k)
    zv[k] = ld_bf4(zp + 256 * k);

  for (int t = 0; t < TB; ++t) {
    float4 zn[4];
    if (t + 1 < TB) {
#pragma unroll
      for (int k = 0; k < 4; ++k)
        zn[k] = ld_bf4(zp + (size_t)(t + 1) * 1024 + 256 * k);
    } else {
#pragma unroll
      for (int k = 0; k < 4; ++k) zn[k] = zv[k];
    }
    const int st = start_at(start, m, sbase + t);
    if (st) {
#pragma unroll
      for (int k = 0; k < 4; ++k) s[k] = zv[k];
    } else {
#pragma unroll
      for (int k = 0; k < 4; ++k) {
        s[k].x += zv[k].x; s[k].y += zv[k].y;
        s[k].z += zv[k].z; s[k].w += zv[k].w;
      }
    }
    float mx = fmaxf(fmaxf(s[0].x, s[0].y), fmaxf(s[0].z, s[0].w));
#pragma unroll
    for (int k = 1; k < 4; ++k)
      mx = fmaxf(mx, fmaxf(fmaxf(s[k].x, s[k].y), fmaxf(s[k].z, s[k].w)));
#pragma unroll
    for (int o = 32; o > 0; o >>= 1) mx = fmaxf(mx, __shfl_xor(mx, o));
    float4 e[4];
    float sum = 0.f;
#pragma unroll
    for (int k = 0; k < 4; ++k) {
      e[k].x = __expf(s[k].x - mx); e[k].y = __expf(s[k].y - mx);
      e[k].z = __expf(s[k].z - mx); e[k].w = __expf(s[k].w - mx);
      sum += (e[k].x + e[k].y) + (e[k].z + e[k].w);
    }
#pragma unroll
    for (int o = 32; o > 0; o >>= 1) sum += __shfl_xor(sum, o);
    const float inv = 1.0f / sum;
#pragma unroll
    for (int k = 0; k < 4; ++k) {
      u16x4 o4;
      o4.x = f2bf(e[k].x * inv); o4.y = f2bf(e[k].y * inv);
      o4.z = f2bf(e[k].z * inv); o4.w = f2bf(e[k].w * inv);
      *(u16x4*)(pp + (size_t)t * 1024 + 256 * k) = o4;
    }
#pragma unroll
    for (int k = 0; k < 4; ++k) zv[k] = zn[k];
  }
}

// ---------------------------------------------------------------------------
__global__ __launch_bounds__(256)
void cvt_x_chunk(const float* __restrict__ x, ushort_t* __restrict__ dst,
                 int t0, int tcShift, int nq) {
  const int i = blockIdx.x * 256 + threadIdx.x;
  if (i >= nq) return;
  const int row = i >> 6, cq = i & 63;
  const int b = row >> tcShift, tl = row & ((1 << tcShift) - 1);
  const float4 v = *(const float4*)(x + ((size_t)b * 4096 + t0 + tl) * 256 + cq * 4);
  u16x4 o;
  o.x = f2bf(v.x); o.y = f2bf(v.y); o.z = f2bf(v.z); o.w = f2bf(v.w);
  *(u16x4*)(dst + (size_t)row * 256 + cq * 4) = o;
}

// ---------------------------------------------------------------------------
__global__ __launch_bounds__(256)
void fill_diag(float* __restrict__ out, int n, float v) {
  const int i = blockIdx.x * 256 + threadIdx.x;
  if (i < n) out[i] = v;
}

// ---------------------------------------------------------------------------
extern "C" void kernel_launch(void* const* d_in, const int* in_sizes, int n_in,
                              void* d_out, int out_size, void* d_ws, size_t ws_size,
                              hipStream_t stream) {
  const float* x    = (const float*)d_in[0];
  const void* start = (const void*)d_in[1];
  const float* Wi   = (const float*)d_in[2];
  const float* bi   = (const float*)d_in[3];
  const float* Wp   = (const float*)d_in[4];
  const float* bp   = (const float*)d_in[5];
  const float* Wf   = (const float*)d_in[6];
  const float* bf_  = (const float*)d_in[7];
  const float* Wo   = (const float*)d_in[8];
  const float* bo   = (const float*)d_in[9];

  const int T = 4096, H = 1024;

  char* ws = (char*)d_ws;
  size_t off = 0;
  auto alloc = [&](size_t bytes) {
    char* p = ws + off; off += (bytes + 255) & ~(size_t)255; return p;
  };

  // --- fixed region. NOTE: wz0,wc0,wc1 contiguous (512KB each, exact) and
  // wp0b,wf0b,wf1b contiguous (2MB each, exact) -> single merged fold-GEMM.
  ushort_t* wz0  = (ushort_t*)alloc((size_t)H * 256 * 2);
  ushort_t* wc0  = (ushort_t*)alloc((size_t)H * 256 * 2);
  ushort_t* wc1  = (ushort_t*)alloc((size_t)H * 256 * 2);
  ushort_t* wp1  = (ushort_t*)alloc((size_t)H * H * 2);
  ushort_t* wf0a = (ushort_t*)alloc((size_t)H * H * 2);
  ushort_t* wf1a = (ushort_t*)alloc((size_t)H * H * 2);
  ushort_t* wob  = (ushort_t*)alloc((size_t)256 * H * 2);
  ushort_t* wiT  = (ushort_t*)alloc((size_t)256 * H * 2);
  ushort_t* wp0b = (ushort_t*)alloc((size_t)H * H * 2);
  ushort_t* wf0b = (ushort_t*)alloc((size_t)H * H * 2);
  ushort_t* wf1b = (ushort_t*)alloc((size_t)H * H * 2);
  float* bz0 = (float*)alloc(H * 4);
  float* bc0 = (float*)alloc(H * 4);
  float* bc1 = (float*)alloc(H * 4);
  float* zeroB = (float*)alloc(256 * 4);
  float* carry0 = (float*)alloc(8192 * 4);
  float* carry1 = (float*)alloc(8192 * 4);
  int* mode = (int*)alloc(256);
  float* aggS    = (float*)alloc((size_t)8 * 256 * 1024 * 4);   // 8 MB (NT<=256)
  float* prefixS = (float*)alloc((size_t)8 * 256 * 1024 * 4);   // 8 MB
  int*   aggF    = (int*)alloc(8 * 256 * 4);
  const size_t fixed = off;

  (void)wc0; (void)wc1; (void)wf0b; (void)wf1b;  // accessed via contiguity

  // --- choose largest fitting T-chunk ---
  auto chunkBytes = [&](int Tc) -> size_t {
    const size_t Mc = (size_t)8 * Tc;
    return Mc * 256 * 2 + 256 + Mc * H * 2 + 256 +
           Mc * H * 2 + 256 + Mc * H * 2 + 256;
  };
  int Tc = 4096;
  while (Tc > 128 && fixed + chunkBytes(Tc) > ws_size) Tc >>= 1;
  if (fixed + chunkBytes(Tc) > ws_size) {
    fill_diag<<<dim3((out_size + 255) / 256), dim3(256), 0, stream>>>(
        (float*)d_out, out_size, (float)(ws_size >> 20));
    return;
  }
  const int Mc = 8 * Tc;
  const int NT = Tc / TB;
  const int tcShift = __builtin_ctz((unsigned)Tc);
  ushort_t* xbc  = (ushort_t*)alloc((size_t)Mc * 256 * 2);
  ushort_t* zbuf = (ushort_t*)alloc((size_t)Mc * H * 2);   // bf16 z
  ushort_t* pbuf = (ushort_t*)alloc((size_t)Mc * H * 2);
  ushort_t* hbuf = (ushort_t*)alloc((size_t)Mc * H * 2);

  const dim3 blk(256);

  auto run_scan_sm = [&](ushort_t* z, float* carry, int first, int t0) {
    scan_p1<<<dim3(32 * NT), blk, 0, stream>>>(z, start, mode, aggS, aggF, t0, Tc, NT);
    scan_p2<<<dim3(32), blk, 0, stream>>>(aggS, aggF, prefixS, carry, first, NT);
    scan_p3sm_wave<<<dim3(8 * NT), dim3(64), 0, stream>>>(
        z, start, mode, prefixS, pbuf, t0, Tc, NT);
  };

  // --- prep: ONE fused dispatch (weights + biases + mode + x chunk-0 cvt) ---
  const int xblocks = (Mc * 64) / 256;   // Mc*64 quads
  prep_all<<<dim3(10498 + xblocks), blk, 0, stream>>>(
      Wp, Wf, Wo, Wi, bi, bp, bf_,
      wp1, wf0a, wf1a, wp0b, wf0b, wf1b, wob, wiT,
      bz0, bc0, bc1, zeroB, (const int*)start, mode, x, xbc, tcShift);

  // merged fold-GEMM: [wz0;wc0;wc1] = [wp0b;wf0b;wf1b] @ wiT^T  (M=3072)
  gemm_bt<false, false, true><<<dim3(2, 24), blk, 0, stream>>>(
      wp0b, H, wp0b, H, wiT, H, wiT, H, H, H, zeroB, wz0, 256, 3072, 0, 0);

  // --- chunked pipeline (Tc=4096 -> single chunk) ---
  const int nch = T / Tc;
  for (int c = 0; c < nch; ++c) {
    const int t0 = c * Tc;
    if (c > 0)
      cvt_x_chunk<<<dim3((Mc * 64 + 255) / 256), blk, 0, stream>>>(
          x, xbc, t0, tcShift, Mc * 64);
    // z0 = x @ (Wp0·Wi)^T + (bp0 + Wp0·bi)   -> bf16 z
    gemm_bt<false, false, true><<<dim3(H / 128, Mc / 128), blk, 0, stream>>>(
        xbc, 256, xbc, 256, wz0, 256, wz0, 256, 256, 256, bz0, zbuf, H, Mc, 0, 0);
    run_scan_sm(zbuf, carry0, c == 0, t0);
    // h0 = leaky( p @ Wf0a^T + x @ (WfB0·Wi)^T + bc0 )
    gemm_bt<true, true, true><<<dim3(H / 128, Mc / 128), blk, 0, stream>>>(
        pbuf, H, xbc, 256, wf0a, H, wc0, 256, H, H + 256, bc0, hbuf, H, Mc, 0, 0);
    // z1 = h0 @ Wp1^T + bp1   -> bf16 z
    gemm_bt<false, false, true><<<dim3(H / 128, Mc / 128), blk, 0, stream>>>(
        hbuf, H, hbuf, H, wp1, H, wp1, H, H, H, bp + H, zbuf, H, Mc, 0, 0);
    run_scan_sm(zbuf, carry1, c == 0, t0);
    // h1 = leaky( p @ Wf1a^T + x @ (WfB1·Wi)^T + bc1 )
    gemm_bt<true, true, true><<<dim3(H / 128, Mc / 128), blk, 0, stream>>>(
        pbuf, H, xbc, 256, wf1a, H, wc1, 256, H, H + 256, bc1, hbuf, H, Mc, 0, 0);
    // out = h1 @ Wo^T + bo  (batch-strided C write into d_out, f32)
    gemm_bt<false, false, false><<<dim3(256 / 128, Mc / 128), blk, 0, stream>>>(
        hbuf, H, hbuf, H, wob, H, wob, H, H, H, bo, (float*)d_out, 256,
        Tc, T, t0);
  }
}